// Round 1
// 5703.584 us; speedup vs baseline: 2.2775x; 2.2775x over previous
//
#include <hip/hip_runtime.h>

typedef unsigned short u16;
using f32x4  = __attribute__((ext_vector_type(4))) float;
using bf16x8 = __attribute__((ext_vector_type(8))) __bf16;

// ---------- helpers ----------
__device__ __forceinline__ float bf2f(u16 s){ return __builtin_bit_cast(float, (unsigned)s << 16); }
__device__ __forceinline__ float bflo(unsigned u){ return __builtin_bit_cast(float, u << 16); }
__device__ __forceinline__ float bfhi(unsigned u){ return __builtin_bit_cast(float, u & 0xffff0000u); }
__device__ __forceinline__ u16 f2bf(float f){
  unsigned u = __builtin_bit_cast(unsigned, f);
  unsigned r = u + 0x7fffu + ((u >> 16) & 1u);
  return (u16)(r >> 16);
}
__device__ __forceinline__ unsigned pk2(float x, float y){
  unsigned ux = __builtin_bit_cast(unsigned, x) + 0x8000u;
  unsigned uy = __builtin_bit_cast(unsigned, y) + 0x8000u;
  return (ux >> 16) | (uy & 0xffff0000u);
}
__device__ __forceinline__ float tanh_f(float x){ float e = __expf(2.f*x); return 1.f - 2.f/(e + 1.f); }
__device__ __forceinline__ float sigm(float x){ return 1.f/(1.f + __expf(-x)); }
__device__ __forceinline__ f32x4 mfma16(bf16x8 a, bf16x8 b, f32x4 c){
  return __builtin_amdgcn_mfma_f32_16x16x32_bf16(a, b, c, 0, 0, 0);
}
__device__ __forceinline__ bf16x8 ldg8(const u16* p){
  return __builtin_bit_cast(bf16x8, *(const uint4*)p);
}
__device__ __forceinline__ bf16x8 cvt8(const float* p){
  float4 a = *(const float4*)p, b = *(const float4*)(p + 4);
  uint4 r; r.x = pk2(a.x, a.y); r.y = pk2(a.z, a.w); r.z = pk2(b.x, b.y); r.w = pk2(b.z, b.w);
  return __builtin_bit_cast(bf16x8, r);
}
__device__ __forceinline__ void gld(const void* g, void* l){
  __builtin_amdgcn_global_load_lds(
      (const __attribute__((address_space(1))) void*)g,
      (__attribute__((address_space(3))) void*)l, 16, 0, 0);
}

// ---------- 128x128 bf16-MFMA GEMM with fp32-or-bf16 operands:
//            C[m,n] = sum_k A[m,k]*B[n,k] (+bias[n]) ----------
template<int EPI, bool AF32, bool BF32>
__global__ __launch_bounds__(256) void gemm_bt(
    const void* __restrict__ Av, int lda,
    const void* __restrict__ Bv, int ldb,
    void* __restrict__ Cv, const float* __restrict__ bias,
    int K, int N)
{
  constexpr int ABYTES = AF32 ? 16384 : 8192;
  constexpr int BBYTES = BF32 ? 16384 : 8192;
  __shared__ __align__(16) unsigned char lsA[ABYTES];
  __shared__ __align__(16) unsigned char lsB[BBYTES];
  const int tid = threadIdx.x;
  const int wv = tid >> 6, l = tid & 63;
  const int m0 = blockIdx.y * 128, n0 = blockIdx.x * 128;
  const int wm = wv & 1, wn = wv >> 1;
  const f32x4 vzero = {0.f, 0.f, 0.f, 0.f};
  f32x4 acc[4][4];
#pragma unroll
  for (int i = 0; i < 4; ++i)
#pragma unroll
    for (int j = 0; j < 4; ++j) acc[i][j] = vzero;

  const float* gAf[4]; const u16* gAh[2]; void* dA[4];
  const float* gBf[4]; const u16* gBh[2]; void* dB[4];
  if constexpr (AF32){
    const float* A = (const float*)Av;
#pragma unroll
    for (int i = 0; i < 4; ++i){
      int e = (wv*4 + i)*64 + l;
      int kc = e >> 8, r = (e >> 1) & 127, h4 = (e & 1)*4;
      gAf[i] = A + (size_t)(m0 + r)*lda + kc*8 + h4;
      dA[i] = lsA + (wv*4 + i)*1024;
    }
  } else {
    const u16* A = (const u16*)Av;
#pragma unroll
    for (int i = 0; i < 2; ++i){
      int e = (wv*2 + i)*64 + l;
      int kc = e >> 7, r = e & 127;
      gAh[i] = A + (size_t)(m0 + r)*lda + kc*8;
      dA[i] = lsA + (wv*2 + i)*1024;
    }
  }
  if constexpr (BF32){
    const float* B = (const float*)Bv;
#pragma unroll
    for (int i = 0; i < 4; ++i){
      int e = (wv*4 + i)*64 + l;
      int kc = e >> 8, r = (e >> 1) & 127, h4 = (e & 1)*4;
      gBf[i] = B + (size_t)(n0 + r)*ldb + kc*8 + h4;
      dB[i] = lsB + (wv*4 + i)*1024;
    }
  } else {
    const u16* B = (const u16*)Bv;
#pragma unroll
    for (int i = 0; i < 2; ++i){
      int e = (wv*2 + i)*64 + l;
      int kc = e >> 7, r = e & 127;
      gBh[i] = B + (size_t)(n0 + r)*ldb + kc*8;
      dB[i] = lsB + (wv*2 + i)*1024;
    }
  }
  const int kq = l >> 4, li = l & 15;

  for (int k0 = 0; k0 < K; k0 += 32){
    __syncthreads();
    if constexpr (AF32){
#pragma unroll
      for (int i = 0; i < 4; ++i) gld(gAf[i] + k0, dA[i]);
    } else {
#pragma unroll
      for (int i = 0; i < 2; ++i) gld(gAh[i] + k0, dA[i]);
    }
    if constexpr (BF32){
#pragma unroll
      for (int i = 0; i < 4; ++i) gld(gBf[i] + k0, dB[i]);
    } else {
#pragma unroll
      for (int i = 0; i < 2; ++i) gld(gBh[i] + k0, dB[i]);
    }
    __syncthreads();
    bf16x8 aF[4], bF[4];
#pragma unroll
    for (int mi = 0; mi < 4; ++mi){
      int idx = kq*128 + wm*64 + mi*16 + li;
      if constexpr (AF32) aF[mi] = cvt8((const float*)lsA + idx*8);
      else                aF[mi] = ldg8((const u16*)lsA + idx*8);
    }
#pragma unroll
    for (int ni = 0; ni < 4; ++ni){
      int idx = kq*128 + wn*64 + ni*16 + li;
      if constexpr (BF32) bF[ni] = cvt8((const float*)lsB + idx*8);
      else                bF[ni] = ldg8((const u16*)lsB + idx*8);
    }
#pragma unroll
    for (int mi = 0; mi < 4; ++mi)
#pragma unroll
      for (int ni = 0; ni < 4; ++ni)
        acc[mi][ni] = mfma16(aF[mi], bF[ni], acc[mi][ni]);
  }

#pragma unroll
  for (int mi = 0; mi < 4; ++mi){
    const int mloc = wm*64 + mi*16 + kq*4;
#pragma unroll
    for (int ni = 0; ni < 4; ++ni){
      const int col = n0 + wn*64 + ni*16 + li;
      f32x4 v = acc[mi][ni];
      if constexpr (EPI == 1){
        float bb = bias ? bias[col] : 0.f;
        u16* C = (u16*)Cv;
#pragma unroll
        for (int r = 0; r < 4; ++r)
          C[(size_t)(m0 + mloc + r)*N + col] = f2bf(v[r] + bb);
      } else if constexpr (EPI == 2){
        float bb = bias[col];
        float* C = (float*)Cv;
#pragma unroll
        for (int r = 0; r < 4; ++r){
          int m = m0 + mloc + r;
          int orow = (m & 15)*128 + (m >> 4);
          C[(size_t)orow*N + col] = v[r] + bb;
        }
      } else { // EPI == 3
        u16* C = (u16*)Cv;
        int m = m0 + mloc;
        int b = m >> 7, s = m & 127;
        unsigned w0 = (unsigned)f2bf(v[0]) | ((unsigned)f2bf(v[1]) << 16);
        unsigned w1 = (unsigned)f2bf(v[2]) | ((unsigned)f2bf(v[3]) << 16);
        uint2 pk; pk.x = w0; pk.y = w1;
        *(uint2*)(C + ((size_t)b*N + col)*128 + s) = pk;
      }
    }
  }
}

// ---------- fp32 -> bf16 cast (8 elems/thread) ----------
__global__ void cast_bf(const float* __restrict__ src, u16* __restrict__ dst, int n8){
  int i = blockIdx.x*256 + threadIdx.x;
  if (i < n8){
    float4 a = ((const float4*)src)[i*2], b = ((const float4*)src)[i*2 + 1];
    uint4 r; r.x = pk2(a.x, a.y); r.y = pk2(a.z, a.w); r.z = pk2(b.x, b.y); r.w = pk2(b.z, b.w);
    ((uint4*)dst)[i] = r;
  }
}

// ---------- embedding gather + cast ----------
__global__ void gather_e(const int* __restrict__ tgt, const float* __restrict__ emb, u16* __restrict__ eall){
  int p = blockIdx.x;           // t*16 + b
  int t = p >> 4, b = p & 15;
  int tok = (t == 0) ? 1 : tgt[b*128 + (t - 1)];
  const float4* src = (const float4*)(emb + (size_t)tok*1024) + threadIdx.x*2;
  float4 a = src[0], c = src[1];
  uint4 r; r.x = pk2(a.x, a.y); r.y = pk2(a.z, a.w); r.z = pk2(c.x, c.y); r.w = pk2(c.z, c.w);
  ((uint4*)(eall + (size_t)p*1024))[threadIdx.x] = r;
}

// init h (fp32) + zero the group-barrier counters (must re-zero every launch)
__global__ void init_h(const float* __restrict__ eh, float* __restrict__ hf, int* __restrict__ bar){
  int i = blockIdx.x*256 + threadIdx.x;
  if (i < 1024) bar[i] = 0;
  hf[i] = eh[i];
}

// ---------- recurrent cooperative kernel: 16 groups x 16 blocks, group-local barriers ----------
struct RP {
  const u16 *Wc, *kproj, *Pt, *ge;   // Wc = [Wq(1024 rows); Whh(3072 rows)] bf16, contiguous
  const float *bhh, *vatt;
  float *q, *gh, *scores, *hf;
  u16 *hseq;
  float *outT, *attw;
  int *bar;
};

// 16-block group barrier. Monotonic counter, one arrive per block (tid 0),
// relaxed spin (no per-poll cache invalidate), single acquire fence on exit.
__device__ __forceinline__ void gbar(int* cnt, int target){
  __syncthreads();                       // drains this block's vmem (compiler emits vmcnt(0))
  if (threadIdx.x == 0){
    __hip_atomic_fetch_add(cnt, 1, __ATOMIC_RELEASE, __HIP_MEMORY_SCOPE_AGENT);
    while (__hip_atomic_load(cnt, __ATOMIC_RELAXED, __HIP_MEMORY_SCOPE_AGENT) < target)
      __builtin_amdgcn_s_sleep(1);
    __builtin_amdgcn_fence(__ATOMIC_ACQUIRE, "agent");
  }
  __syncthreads();
}

__global__ __launch_bounds__(256) void rec_kernel(RP p){
  __shared__ float shm[1024];   // phase1: h[1024]; phase3: wf = shm[0..128), gcv = shm[128..320)
  const int tid = threadIdx.x;
  const int blk = blockIdx.x;
  const int b = blk >> 4, ic = blk & 15;   // group = batch b, member ic; XCD = blk%8 = ic%8
  const int wv = tid >> 6, l = tid & 63;
  int* cnt = p.bar + b*32;                 // 128B-strided per-group counter
  int target = 0;

  // this thread's fixed GEMV row of W' = [Wq; Whh]
  const int r = ic*256 + tid;
  const u16* wr = p.Wc + (size_t)r*1024;
  float* qout = (r < 1024) ? (p.q + b*1024 + r) : (p.gh + b*3072 + (r - 1024));
  const float badd = (r < 1024) ? 0.f : p.bhh[r - 1024];

  for (int t = 0; t < 128; ++t){
    // ---- phase 1: q = h@Wq^T ; gh = h@Whh^T + bhh   (fp32 h x bf16 W GEMV) ----
    ((float4*)shm)[tid] = ((const float4*)(p.hf + b*1024))[tid];
    __syncthreads();
    {
      float a0 = 0.f, a1 = 0.f, a2 = 0.f, a3 = 0.f;
#pragma unroll 8
      for (int k0 = 0; k0 < 1024; k0 += 8){
        uint4 u = *(const uint4*)(wr + k0);
        a0 += shm[k0+0]*bflo(u.x) + shm[k0+1]*bfhi(u.x);
        a1 += shm[k0+2]*bflo(u.y) + shm[k0+3]*bfhi(u.y);
        a2 += shm[k0+4]*bflo(u.z) + shm[k0+5]*bfhi(u.z);
        a3 += shm[k0+6]*bflo(u.w) + shm[k0+7]*bfhi(u.w);
      }
      *qout = (a0 + a1) + (a2 + a3) + badd;
    }
    target += 16; gbar(cnt, target);

    // ---- phase 2: scores[b,s] = sum_h v[h]*tanh(q[b,h] + kproj[b,s,h]) ----
    {
#pragma unroll
      for (int si = 0; si < 2; ++si){
        int s = ic*8 + wv*2 + si;
        const uint4* kp = (const uint4*)(p.kproj + ((size_t)(b*128 + s))*1024) + l*2;
        const float4* qp = (const float4*)(p.q + b*1024) + l*4;
        const float4* vp = (const float4*)(p.vatt) + l*4;
        uint4 ka = kp[0], kb = kp[1];
        float4 v0 = vp[0], v1 = vp[1], v2 = vp[2], v3 = vp[3];
        float4 q0 = qp[0], q1 = qp[1], q2 = qp[2], q3 = qp[3];
        float acc = 0.f;
        acc += v0.x*tanh_f(q0.x + bflo(ka.x)) + v0.y*tanh_f(q0.y + bfhi(ka.x));
        acc += v0.z*tanh_f(q0.z + bflo(ka.y)) + v0.w*tanh_f(q0.w + bfhi(ka.y));
        acc += v1.x*tanh_f(q1.x + bflo(ka.z)) + v1.y*tanh_f(q1.y + bfhi(ka.z));
        acc += v1.z*tanh_f(q1.z + bflo(ka.w)) + v1.w*tanh_f(q1.w + bfhi(ka.w));
        acc += v2.x*tanh_f(q2.x + bflo(kb.x)) + v2.y*tanh_f(q2.y + bfhi(kb.x));
        acc += v2.z*tanh_f(q2.z + bflo(kb.y)) + v2.w*tanh_f(q2.w + bfhi(kb.y));
        acc += v3.x*tanh_f(q3.x + bflo(kb.z)) + v3.y*tanh_f(q3.y + bfhi(kb.z));
        acc += v3.z*tanh_f(q3.z + bflo(kb.w)) + v3.w*tanh_f(q3.w + bfhi(kb.w));
#pragma unroll
        for (int o = 32; o; o >>= 1) acc += __shfl_xor(acc, o);
        if (l == 0) p.scores[b*128 + s] = acc;
      }
    }
    target += 16; gbar(cnt, target);

    // ---- phase 3: softmax + gc (via Pt) + GRU update ----
    {
      float* wf  = shm;
      float* gcv = shm + 128;
      if (wv == 0){
        float x0 = p.scores[b*128 + l], x1 = p.scores[b*128 + 64 + l];
        float m = fmaxf(x0, x1);
#pragma unroll
        for (int o = 32; o; o >>= 1) m = fmaxf(m, __shfl_xor(m, o));
        float e0 = __expf(x0 - m), e1 = __expf(x1 - m);
        float sm = e0 + e1;
#pragma unroll
        for (int o = 32; o; o >>= 1) sm += __shfl_xor(sm, o);
        float inv = 1.f / sm;
        wf[l] = e0*inv; wf[64 + l] = e1*inv;
      }
      __syncthreads();
      if (tid < 192){
        int gate = tid >> 6, ii = tid & 63;
        int j = gate*1024 + ic*64 + ii;
        const uint4* pr = (const uint4*)(p.Pt + ((size_t)(b*3072 + j))*128);
        float acc = 0.f;
#pragma unroll
        for (int c = 0; c < 16; ++c){
          uint4 u = pr[c];
          const float* w8 = &wf[c*8];
          acc += w8[0]*bflo(u.x) + w8[1]*bfhi(u.x)
               + w8[2]*bflo(u.y) + w8[3]*bfhi(u.y)
               + w8[4]*bflo(u.z) + w8[5]*bfhi(u.z)
               + w8[6]*bflo(u.w) + w8[7]*bfhi(u.w);
        }
        gcv[tid] = acc;
      }
      __syncthreads();
      if (tid < 64){
        int i = ic*64 + tid;
        size_t mrow = (size_t)(t*16 + b);
        const u16* gep = p.ge + mrow*3072;
        float ger = bf2f(gep[i]), gez = bf2f(gep[i + 1024]), gen = bf2f(gep[i + 2048]);
        const float* ghp = p.gh + b*3072;
        float ghr = ghp[i], ghz = ghp[i + 1024], ghn = ghp[i + 2048];
        float rg = sigm(ger + gcv[tid] + ghr);
        float z  = sigm(gez + gcv[64 + tid] + ghz);
        float n  = tanh_f(gen + gcv[128 + tid] + rg*ghn);
        float hp = p.hf[b*1024 + i];
        float hn = (1.f - z)*n + z*hp;
        p.hf[b*1024 + i] = hn;
        p.hseq[mrow*1024 + i] = f2bf(hn);
        if (t == 127) p.outT[b*1024 + i] = hn;
      }
      if (ic == 0 && tid < 128){
        p.attw[((size_t)(b*128 + t))*128 + tid] = wf[tid];
      }
    }
    target += 16; gbar(cnt, target);
  }
}

// ---------- logsumexp over V per output row, then in-place fixup ----------
__global__ __launch_bounds__(256) void lse_kernel(const float* __restrict__ outp, float* __restrict__ lse){
  __shared__ float rm[256], rs[256];
  int r = blockIdx.x, tid = threadIdx.x;
  const float4* rp = (const float4*)(outp + (size_t)r*32000);
  float m = -3.0e38f, s = 0.f;
  for (int v = tid; v < 8000; v += 256){
    float4 x = rp[v];
    float mx = fmaxf(fmaxf(x.x, x.y), fmaxf(x.z, x.w));
    if (mx > m){ s *= __expf(m - mx); m = mx; }
    s += __expf(x.x - m) + __expf(x.y - m) + __expf(x.z - m) + __expf(x.w - m);
  }
  rm[tid] = m; rs[tid] = s;
  __syncthreads();
  for (int o = 128; o; o >>= 1){
    if (tid < o){
      float m2 = rm[tid + o], s2 = rs[tid + o], m1 = rm[tid], s1 = rs[tid];
      float M = fmaxf(m1, m2);
      rs[tid] = s1*__expf(m1 - M) + s2*__expf(m2 - M);
      rm[tid] = M;
    }
    __syncthreads();
  }
  if (tid == 0) lse[r] = rm[0] + __logf(rs[0]);
}

__global__ __launch_bounds__(256) void fixup_kernel(float* __restrict__ outp, const float* __restrict__ lse){
  int idx = blockIdx.x*256 + threadIdx.x;
  int r = idx / 8000;
  float L = lse[r];
  float4* p4 = (float4*)outp;
  float4 u = p4[idx];
  u.x -= L; u.y -= L; u.z -= L; u.w -= L;
  p4[idx] = u;
}

// ---------- host ----------
extern "C" void kernel_launch(void* const* d_in, const int* in_sizes, int n_in,
                              void* d_out, int out_size, void* d_ws, size_t ws_size,
                              hipStream_t stream) {
  (void)in_sizes; (void)n_in; (void)out_size; (void)ws_size;
  const float* eo   = (const float*)d_in[0];
  const float* eh   = (const float*)d_in[1];
  const int*   tgt  = (const int*)d_in[2];
  const float* emb  = (const float*)d_in[3];
  const float* Wq   = (const float*)d_in[4];
  const float* Wk   = (const float*)d_in[5];
  const float* vatt = (const float*)d_in[6];
  const float* Wih  = (const float*)d_in[7];
  const float* Whh  = (const float*)d_in[8];
  const float* bih  = (const float*)d_in[9];
  const float* bhh  = (const float*)d_in[10];
  const float* Wout = (const float*)d_in[11];
  const float* bout = (const float*)d_in[12];
  float* out = (float*)d_out;

  char* ws = (char*)d_ws;
  u16*  kproj = (u16*) (ws + 0);          //  4 MiB  [16*128][1024] bf16
  u16*  ge    = (u16*) (ws + 4194304);    // 12 MiB  [128*16][3072] bf16 (incl b_ih)
  u16*  Pt    = (u16*) (ws + 16777216);   // 12 MiB  [16][3072][128] bf16
  u16*  eall  = (u16*) (ws + 29360128);   //  4 MiB  [128*16][1024] bf16
  u16*  hseq  = (u16*) (ws + 33554432);   //  4 MiB  [128*16][1024] bf16
  u16*  wqb   = (u16*) (ws + 37748736);   //  2 MiB  bf16 Wq   (rows 0..1023 of Wc)
  u16*  whhb  = (u16*) (ws + 39845888);   //  6 MiB  bf16 Whh  (rows 1024..4095 of Wc, contiguous)
  float* hf   = (float*)(ws + 46137344);  // 64 KiB  [16][1024] f32
  int*  bar   = (int*)  (ws + 46202880);  // 32 KiB  (old hbf slot) group-barrier counters
  float* q    = (float*)(ws + 46235648);  // 64 KiB
  float* gh   = (float*)(ws + 46301184);  // 192 KiB
  float* sc   = (float*)(ws + 46497792);  //  8 KiB
  float* lse  = (float*)(ws + 46505984);  //  8 KiB

  float* outT = out + 65536000;
  float* attw = out + 65552384;

  cast_bf<<<512, 256, 0, stream>>>(Wq, wqb, 131072);
  cast_bf<<<1536, 256, 0, stream>>>(Whh, whhb, 393216);
  gather_e<<<2048, 128, 0, stream>>>(tgt, emb, eall);
  init_h<<<64, 256, 0, stream>>>(eh, hf, bar);

  gemm_bt<1, true, true><<<dim3(8, 16), 256, 0, stream>>>(eo, 1024, Wk, 1024, kproj, nullptr, 1024, 1024);
  gemm_bt<1, false, true><<<dim3(24, 16), 256, 0, stream>>>(eall, 1024, Wih, 2048, ge, bih, 1024, 3072);
  gemm_bt<3, true, true><<<dim3(24, 16), 256, 0, stream>>>(eo, 1024, Wih + 1024, 2048, Pt, nullptr, 1024, 3072);

  RP rp;
  rp.Wc = wqb; rp.kproj = kproj; rp.Pt = Pt; rp.ge = ge;
  rp.bhh = bhh; rp.vatt = vatt;
  rp.q = q; rp.gh = gh; rp.scores = sc; rp.hf = hf;
  rp.hseq = hseq; rp.outT = outT; rp.attw = attw;
  rp.bar = bar;
  void* kargs[] = { (void*)&rp };
  hipLaunchCooperativeKernel((void*)rec_kernel, dim3(256), dim3(256), kargs, 0, stream);

  gemm_bt<2, false, true><<<dim3(250, 16), 256, 0, stream>>>(hseq, 1024, Wout, 1024, out, bout, 1024, 32000);
  lse_kernel<<<2048, 256, 0, stream>>>(out, lse);
  fixup_kernel<<<64000, 256, 0, stream>>>(out, lse);
}

// Round 2
// 4271.716 us; speedup vs baseline: 3.0409x; 1.3352x over previous
//
#include <hip/hip_runtime.h>

typedef unsigned short u16;
using f32x4  = __attribute__((ext_vector_type(4))) float;
using bf16x8 = __attribute__((ext_vector_type(8))) __bf16;

// ---------- helpers ----------
__device__ __forceinline__ float bf2f(u16 s){ return __builtin_bit_cast(float, (unsigned)s << 16); }
__device__ __forceinline__ float bflo(unsigned u){ return __builtin_bit_cast(float, u << 16); }
__device__ __forceinline__ float bfhi(unsigned u){ return __builtin_bit_cast(float, u & 0xffff0000u); }
__device__ __forceinline__ u16 f2bf(float f){
  unsigned u = __builtin_bit_cast(unsigned, f);
  unsigned r = u + 0x7fffu + ((u >> 16) & 1u);
  return (u16)(r >> 16);
}
__device__ __forceinline__ unsigned pk2(float x, float y){
  unsigned ux = __builtin_bit_cast(unsigned, x) + 0x8000u;
  unsigned uy = __builtin_bit_cast(unsigned, y) + 0x8000u;
  return (ux >> 16) | (uy & 0xffff0000u);
}
__device__ __forceinline__ float tanh_f(float x){ float e = __expf(2.f*x); return 1.f - 2.f/(e + 1.f); }
__device__ __forceinline__ float sigm(float x){ return 1.f/(1.f + __expf(-x)); }
__device__ __forceinline__ f32x4 mfma16(bf16x8 a, bf16x8 b, f32x4 c){
  return __builtin_amdgcn_mfma_f32_16x16x32_bf16(a, b, c, 0, 0, 0);
}
__device__ __forceinline__ bf16x8 ldg8(const u16* p){
  return __builtin_bit_cast(bf16x8, *(const uint4*)p);
}
__device__ __forceinline__ bf16x8 cvt8(const float* p){
  float4 a = *(const float4*)p, b = *(const float4*)(p + 4);
  uint4 r; r.x = pk2(a.x, a.y); r.y = pk2(a.z, a.w); r.z = pk2(b.x, b.y); r.w = pk2(b.z, b.w);
  return __builtin_bit_cast(bf16x8, r);
}
__device__ __forceinline__ void gld(const void* g, void* l){
  __builtin_amdgcn_global_load_lds(
      (const __attribute__((address_space(1))) void*)g,
      (__attribute__((address_space(3))) void*)l, 16, 0, 0);
}

// coherent (MALL-level) scalar access: bypasses non-coherent per-XCD L2,
// so cross-block data is visible WITHOUT any L2 writeback/invalidate fences.
__device__ __forceinline__ float coh_ld(const float* p){
  return __hip_atomic_load(p, __ATOMIC_RELAXED, __HIP_MEMORY_SCOPE_AGENT);
}
__device__ __forceinline__ void coh_st(float* p, float v){
  __hip_atomic_store(p, v, __ATOMIC_RELAXED, __HIP_MEMORY_SCOPE_AGENT);
}

// ---------- 128x128 bf16-MFMA GEMM with fp32-or-bf16 operands:
//            C[m,n] = sum_k A[m,k]*B[n,k] (+bias[n]) ----------
template<int EPI, bool AF32, bool BF32>
__global__ __launch_bounds__(256) void gemm_bt(
    const void* __restrict__ Av, int lda,
    const void* __restrict__ Bv, int ldb,
    void* __restrict__ Cv, const float* __restrict__ bias,
    int K, int N)
{
  constexpr int ABYTES = AF32 ? 16384 : 8192;
  constexpr int BBYTES = BF32 ? 16384 : 8192;
  __shared__ __align__(16) unsigned char lsA[ABYTES];
  __shared__ __align__(16) unsigned char lsB[BBYTES];
  const int tid = threadIdx.x;
  const int wv = tid >> 6, l = tid & 63;
  const int m0 = blockIdx.y * 128, n0 = blockIdx.x * 128;
  const int wm = wv & 1, wn = wv >> 1;
  const f32x4 vzero = {0.f, 0.f, 0.f, 0.f};
  f32x4 acc[4][4];
#pragma unroll
  for (int i = 0; i < 4; ++i)
#pragma unroll
    for (int j = 0; j < 4; ++j) acc[i][j] = vzero;

  const float* gAf[4]; const u16* gAh[2]; void* dA[4];
  const float* gBf[4]; const u16* gBh[2]; void* dB[4];
  if constexpr (AF32){
    const float* A = (const float*)Av;
#pragma unroll
    for (int i = 0; i < 4; ++i){
      int e = (wv*4 + i)*64 + l;
      int kc = e >> 8, r = (e >> 1) & 127, h4 = (e & 1)*4;
      gAf[i] = A + (size_t)(m0 + r)*lda + kc*8 + h4;
      dA[i] = lsA + (wv*4 + i)*1024;
    }
  } else {
    const u16* A = (const u16*)Av;
#pragma unroll
    for (int i = 0; i < 2; ++i){
      int e = (wv*2 + i)*64 + l;
      int kc = e >> 7, r = e & 127;
      gAh[i] = A + (size_t)(m0 + r)*lda + kc*8;
      dA[i] = lsA + (wv*2 + i)*1024;
    }
  }
  if constexpr (BF32){
    const float* B = (const float*)Bv;
#pragma unroll
    for (int i = 0; i < 4; ++i){
      int e = (wv*4 + i)*64 + l;
      int kc = e >> 8, r = (e >> 1) & 127, h4 = (e & 1)*4;
      gBf[i] = B + (size_t)(n0 + r)*ldb + kc*8 + h4;
      dB[i] = lsB + (wv*4 + i)*1024;
    }
  } else {
    const u16* B = (const u16*)Bv;
#pragma unroll
    for (int i = 0; i < 2; ++i){
      int e = (wv*2 + i)*64 + l;
      int kc = e >> 7, r = e & 127;
      gBh[i] = B + (size_t)(n0 + r)*ldb + kc*8;
      dB[i] = lsB + (wv*2 + i)*1024;
    }
  }
  const int kq = l >> 4, li = l & 15;

  for (int k0 = 0; k0 < K; k0 += 32){
    __syncthreads();
    if constexpr (AF32){
#pragma unroll
      for (int i = 0; i < 4; ++i) gld(gAf[i] + k0, dA[i]);
    } else {
#pragma unroll
      for (int i = 0; i < 2; ++i) gld(gAh[i] + k0, dA[i]);
    }
    if constexpr (BF32){
#pragma unroll
      for (int i = 0; i < 4; ++i) gld(gBf[i] + k0, dB[i]);
    } else {
#pragma unroll
      for (int i = 0; i < 2; ++i) gld(gBh[i] + k0, dB[i]);
    }
    __syncthreads();
    bf16x8 aF[4], bF[4];
#pragma unroll
    for (int mi = 0; mi < 4; ++mi){
      int idx = kq*128 + wm*64 + mi*16 + li;
      if constexpr (AF32) aF[mi] = cvt8((const float*)lsA + idx*8);
      else                aF[mi] = ldg8((const u16*)lsA + idx*8);
    }
#pragma unroll
    for (int ni = 0; ni < 4; ++ni){
      int idx = kq*128 + wn*64 + ni*16 + li;
      if constexpr (BF32) bF[ni] = cvt8((const float*)lsB + idx*8);
      else                bF[ni] = ldg8((const u16*)lsB + idx*8);
    }
#pragma unroll
    for (int mi = 0; mi < 4; ++mi)
#pragma unroll
      for (int ni = 0; ni < 4; ++ni)
        acc[mi][ni] = mfma16(aF[mi], bF[ni], acc[mi][ni]);
  }

#pragma unroll
  for (int mi = 0; mi < 4; ++mi){
    const int mloc = wm*64 + mi*16 + kq*4;
#pragma unroll
    for (int ni = 0; ni < 4; ++ni){
      const int col = n0 + wn*64 + ni*16 + li;
      f32x4 v = acc[mi][ni];
      if constexpr (EPI == 1){
        float bb = bias ? bias[col] : 0.f;
        u16* C = (u16*)Cv;
#pragma unroll
        for (int r = 0; r < 4; ++r)
          C[(size_t)(m0 + mloc + r)*N + col] = f2bf(v[r] + bb);
      } else if constexpr (EPI == 2){
        float bb = bias[col];
        float* C = (float*)Cv;
#pragma unroll
        for (int r = 0; r < 4; ++r){
          int m = m0 + mloc + r;
          int orow = (m & 15)*128 + (m >> 4);
          C[(size_t)orow*N + col] = v[r] + bb;
        }
      } else { // EPI == 3
        u16* C = (u16*)Cv;
        int m = m0 + mloc;
        int b = m >> 7, s = m & 127;
        unsigned w0 = (unsigned)f2bf(v[0]) | ((unsigned)f2bf(v[1]) << 16);
        unsigned w1 = (unsigned)f2bf(v[2]) | ((unsigned)f2bf(v[3]) << 16);
        uint2 pk; pk.x = w0; pk.y = w1;
        *(uint2*)(C + ((size_t)b*N + col)*128 + s) = pk;
      }
    }
  }
}

// ---------- fp32 -> bf16 cast (8 elems/thread) ----------
__global__ void cast_bf(const float* __restrict__ src, u16* __restrict__ dst, int n8){
  int i = blockIdx.x*256 + threadIdx.x;
  if (i < n8){
    float4 a = ((const float4*)src)[i*2], b = ((const float4*)src)[i*2 + 1];
    uint4 r; r.x = pk2(a.x, a.y); r.y = pk2(a.z, a.w); r.z = pk2(b.x, b.y); r.w = pk2(b.z, b.w);
    ((uint4*)dst)[i] = r;
  }
}

// ---------- embedding gather + cast ----------
__global__ void gather_e(const int* __restrict__ tgt, const float* __restrict__ emb, u16* __restrict__ eall){
  int p = blockIdx.x;           // t*16 + b
  int t = p >> 4, b = p & 15;
  int tok = (t == 0) ? 1 : tgt[b*128 + (t - 1)];
  const float4* src = (const float4*)(emb + (size_t)tok*1024) + threadIdx.x*2;
  float4 a = src[0], c = src[1];
  uint4 r; r.x = pk2(a.x, a.y); r.y = pk2(a.z, a.w); r.z = pk2(c.x, c.y); r.w = pk2(c.z, c.w);
  ((uint4*)(eall + (size_t)p*1024))[threadIdx.x] = r;
}

// init h (fp32) + zero the group-barrier counters (must re-zero every launch)
__global__ void init_h(const float* __restrict__ eh, float* __restrict__ hf, int* __restrict__ bar){
  int i = blockIdx.x*256 + threadIdx.x;
  if (i < 1024) bar[i] = 0;
  hf[i] = eh[i];
}

// ---------- recurrent cooperative kernel: 16 groups x 16 blocks, group-local barriers ----------
struct RP {
  const u16 *Wc, *kproj, *Pt, *ge;   // Wc = [Wq(1024 rows); Whh(3072 rows)] bf16, contiguous
  const float *bhh, *vatt;
  float *q, *gh, *scores, *hf;
  u16 *hseq;
  float *outT, *attw;
  int *bar;
};

// 16-block fence-free barrier. All cross-block data moves via coh_st/coh_ld
// (write-through to MALL), so NO buffer_wbl2 / buffer_inv is needed here —
// per-XCD L2 contents (weights, kproj, Pt) stay resident across all steps.
// __syncthreads() drains vmcnt (stores visible at MALL) before the arrive.
__device__ __forceinline__ void gbar(int* cnt, int target){
  __syncthreads();
  if (threadIdx.x == 0){
    __hip_atomic_fetch_add(cnt, 1, __ATOMIC_RELAXED, __HIP_MEMORY_SCOPE_AGENT);
    while (__hip_atomic_load(cnt, __ATOMIC_RELAXED, __HIP_MEMORY_SCOPE_AGENT) < target)
      __builtin_amdgcn_s_sleep(1);
  }
  __syncthreads();
}

__global__ __launch_bounds__(256) void rec_kernel(RP p){
  __shared__ float shm[1024];   // phase1: h[1024]; phase3: wf = shm[0..128), gcv = shm[128..320)
  const int tid = threadIdx.x;
  const int blk = blockIdx.x;
  const int b = blk >> 4, ic = blk & 15;   // group = batch b, member ic; XCD = blk%8 = ic%8
  const int wv = tid >> 6, l = tid & 63;
  int* cnt = p.bar + b*32;                 // 128B-strided per-group counter
  int target = 0;

  // this thread's fixed GEMV row of W' = [Wq; Whh]
  const int r = ic*256 + tid;
  const u16* wr = p.Wc + (size_t)r*1024;
  float* qout = (r < 1024) ? (p.q + b*1024 + r) : (p.gh + b*3072 + (r - 1024));
  const float badd = (r < 1024) ? 0.f : p.bhh[r - 1024];

  // persistent h slice owned by this block: i = ic*64 + tid (tid < 64)
  float hreg = (tid < 64) ? p.hf[b*1024 + ic*64 + tid] : 0.f;

  for (int t = 0; t < 128; ++t){
    // ---- phase 1: q = h@Wq^T ; gh = h@Whh^T + bhh   (fp32 h x bf16 W GEMV) ----
    {
      const float* hfb = p.hf + b*1024 + tid*4;
      float4 hv;
      hv.x = coh_ld(hfb + 0); hv.y = coh_ld(hfb + 1);
      hv.z = coh_ld(hfb + 2); hv.w = coh_ld(hfb + 3);
      ((float4*)shm)[tid] = hv;
    }
    __syncthreads();
    {
      float a0 = 0.f, a1 = 0.f, a2 = 0.f, a3 = 0.f;
#pragma unroll 8
      for (int k0 = 0; k0 < 1024; k0 += 8){
        uint4 u = *(const uint4*)(wr + k0);
        a0 += shm[k0+0]*bflo(u.x) + shm[k0+1]*bfhi(u.x);
        a1 += shm[k0+2]*bflo(u.y) + shm[k0+3]*bfhi(u.y);
        a2 += shm[k0+4]*bflo(u.z) + shm[k0+5]*bfhi(u.z);
        a3 += shm[k0+6]*bflo(u.w) + shm[k0+7]*bfhi(u.w);
      }
      coh_st(qout, (a0 + a1) + (a2 + a3) + badd);
    }
    target += 16; gbar(cnt, target);

    // ---- phase 2: scores[b,s] = sum_h v[h]*tanh(q[b,h] + kproj[b,s,h]) ----
    {
      float qv[16];
      const float* qb = p.q + b*1024 + l*16;
#pragma unroll
      for (int j = 0; j < 16; ++j) qv[j] = coh_ld(qb + j);
      const float4* vp = (const float4*)(p.vatt) + l*4;
      float4 v0 = vp[0], v1 = vp[1], v2 = vp[2], v3 = vp[3];
#pragma unroll
      for (int si = 0; si < 2; ++si){
        int s = ic*8 + wv*2 + si;
        const uint4* kp = (const uint4*)(p.kproj + ((size_t)(b*128 + s))*1024) + l*2;
        uint4 ka = kp[0], kb = kp[1];
        float acc = 0.f;
        acc += v0.x*tanh_f(qv[0]  + bflo(ka.x)) + v0.y*tanh_f(qv[1]  + bfhi(ka.x));
        acc += v0.z*tanh_f(qv[2]  + bflo(ka.y)) + v0.w*tanh_f(qv[3]  + bfhi(ka.y));
        acc += v1.x*tanh_f(qv[4]  + bflo(ka.z)) + v1.y*tanh_f(qv[5]  + bfhi(ka.z));
        acc += v1.z*tanh_f(qv[6]  + bflo(ka.w)) + v1.w*tanh_f(qv[7]  + bfhi(ka.w));
        acc += v2.x*tanh_f(qv[8]  + bflo(kb.x)) + v2.y*tanh_f(qv[9]  + bfhi(kb.x));
        acc += v2.z*tanh_f(qv[10] + bflo(kb.y)) + v2.w*tanh_f(qv[11] + bfhi(kb.y));
        acc += v3.x*tanh_f(qv[12] + bflo(kb.z)) + v3.y*tanh_f(qv[13] + bfhi(kb.z));
        acc += v3.z*tanh_f(qv[14] + bflo(kb.w)) + v3.w*tanh_f(qv[15] + bfhi(kb.w));
#pragma unroll
        for (int o = 32; o; o >>= 1) acc += __shfl_xor(acc, o);
        if (l == 0) coh_st(p.scores + b*128 + s, acc);
      }
    }
    target += 16; gbar(cnt, target);

    // ---- phase 3: softmax + gc (via Pt) + GRU update ----
    {
      float* wf  = shm;
      float* gcv = shm + 128;
      if (wv == 0){
        float x0 = coh_ld(p.scores + b*128 + l);
        float x1 = coh_ld(p.scores + b*128 + 64 + l);
        float m = fmaxf(x0, x1);
#pragma unroll
        for (int o = 32; o; o >>= 1) m = fmaxf(m, __shfl_xor(m, o));
        float e0 = __expf(x0 - m), e1 = __expf(x1 - m);
        float sm = e0 + e1;
#pragma unroll
        for (int o = 32; o; o >>= 1) sm += __shfl_xor(sm, o);
        float inv = 1.f / sm;
        wf[l] = e0*inv; wf[64 + l] = e1*inv;
      }
      __syncthreads();
      if (tid < 192){
        int gate = tid >> 6, ii = tid & 63;
        int j = gate*1024 + ic*64 + ii;
        const uint4* pr = (const uint4*)(p.Pt + ((size_t)(b*3072 + j))*128);
        float acc = 0.f;
#pragma unroll
        for (int c = 0; c < 16; ++c){
          uint4 u = pr[c];
          const float* w8 = &wf[c*8];
          acc += w8[0]*bflo(u.x) + w8[1]*bfhi(u.x)
               + w8[2]*bflo(u.y) + w8[3]*bfhi(u.y)
               + w8[4]*bflo(u.z) + w8[5]*bfhi(u.z)
               + w8[6]*bflo(u.w) + w8[7]*bfhi(u.w);
        }
        gcv[tid] = acc;
      }
      __syncthreads();
      if (tid < 64){
        int i = ic*64 + tid;
        size_t mrow = (size_t)(t*16 + b);
        const u16* gep = p.ge + mrow*3072;
        float ger = bf2f(gep[i]), gez = bf2f(gep[i + 1024]), gen = bf2f(gep[i + 2048]);
        const float* ghp = p.gh + b*3072;
        float ghr = coh_ld(ghp + i);
        float ghz = coh_ld(ghp + i + 1024);
        float ghn = coh_ld(ghp + i + 2048);
        float rg = sigm(ger + gcv[tid] + ghr);
        float z  = sigm(gez + gcv[64 + tid] + ghz);
        float n  = tanh_f(gen + gcv[128 + tid] + rg*ghn);
        float hn = (1.f - z)*n + z*hreg;
        hreg = hn;
        coh_st(p.hf + b*1024 + i, hn);
        p.hseq[mrow*1024 + i] = f2bf(hn);
        if (t == 127) p.outT[b*1024 + i] = hn;
      }
      if (ic == 0 && tid < 128){
        p.attw[((size_t)(b*128 + t))*128 + tid] = wf[tid];
      }
    }
    target += 16; gbar(cnt, target);
  }
}

// ---------- logsumexp over V per output row, then in-place fixup ----------
__global__ __launch_bounds__(256) void lse_kernel(const float* __restrict__ outp, float* __restrict__ lse){
  __shared__ float rm[256], rs[256];
  int r = blockIdx.x, tid = threadIdx.x;
  const float4* rp = (const float4*)(outp + (size_t)r*32000);
  float m = -3.0e38f, s = 0.f;
  for (int v = tid; v < 8000; v += 256){
    float4 x = rp[v];
    float mx = fmaxf(fmaxf(x.x, x.y), fmaxf(x.z, x.w));
    if (mx > m){ s *= __expf(m - mx); m = mx; }
    s += __expf(x.x - m) + __expf(x.y - m) + __expf(x.z - m) + __expf(x.w - m);
  }
  rm[tid] = m; rs[tid] = s;
  __syncthreads();
  for (int o = 128; o; o >>= 1){
    if (tid < o){
      float m2 = rm[tid + o], s2 = rs[tid + o], m1 = rm[tid], s1 = rs[tid];
      float M = fmaxf(m1, m2);
      rs[tid] = s1*__expf(m1 - M) + s2*__expf(m2 - M);
      rm[tid] = M;
    }
    __syncthreads();
  }
  if (tid == 0) lse[r] = rm[0] + __logf(rs[0]);
}

__global__ __launch_bounds__(256) void fixup_kernel(float* __restrict__ outp, const float* __restrict__ lse){
  int idx = blockIdx.x*256 + threadIdx.x;
  int r = idx / 8000;
  float L = lse[r];
  float4* p4 = (float4*)outp;
  float4 u = p4[idx];
  u.x -= L; u.y -= L; u.z -= L; u.w -= L;
  p4[idx] = u;
}

// ---------- host ----------
extern "C" void kernel_launch(void* const* d_in, const int* in_sizes, int n_in,
                              void* d_out, int out_size, void* d_ws, size_t ws_size,
                              hipStream_t stream) {
  (void)in_sizes; (void)n_in; (void)out_size; (void)ws_size;
  const float* eo   = (const float*)d_in[0];
  const float* eh   = (const float*)d_in[1];
  const int*   tgt  = (const int*)d_in[2];
  const float* emb  = (const float*)d_in[3];
  const float* Wq   = (const float*)d_in[4];
  const float* Wk   = (const float*)d_in[5];
  const float* vatt = (const float*)d_in[6];
  const float* Wih  = (const float*)d_in[7];
  const float* Whh  = (const float*)d_in[8];
  const float* bih  = (const float*)d_in[9];
  const float* bhh  = (const float*)d_in[10];
  const float* Wout = (const float*)d_in[11];
  const float* bout = (const float*)d_in[12];
  float* out = (float*)d_out;

  char* ws = (char*)d_ws;
  u16*  kproj = (u16*) (ws + 0);          //  4 MiB  [16*128][1024] bf16
  u16*  ge    = (u16*) (ws + 4194304);    // 12 MiB  [128*16][3072] bf16 (incl b_ih)
  u16*  Pt    = (u16*) (ws + 16777216);   // 12 MiB  [16][3072][128] bf16
  u16*  eall  = (u16*) (ws + 29360128);   //  4 MiB  [128*16][1024] bf16
  u16*  hseq  = (u16*) (ws + 33554432);   //  4 MiB  [128*16][1024] bf16
  u16*  wqb   = (u16*) (ws + 37748736);   //  2 MiB  bf16 Wq   (rows 0..1023 of Wc)
  u16*  whhb  = (u16*) (ws + 39845888);   //  6 MiB  bf16 Whh  (rows 1024..4095 of Wc, contiguous)
  float* hf   = (float*)(ws + 46137344);  // 64 KiB  [16][1024] f32
  int*  bar   = (int*)  (ws + 46202880);  // 32 KiB  group-barrier counters
  float* q    = (float*)(ws + 46235648);  // 64 KiB
  float* gh   = (float*)(ws + 46301184);  // 192 KiB
  float* sc   = (float*)(ws + 46497792);  //  8 KiB
  float* lse  = (float*)(ws + 46505984);  //  8 KiB

  float* outT = out + 65536000;
  float* attw = out + 65552384;

  cast_bf<<<512, 256, 0, stream>>>(Wq, wqb, 131072);
  cast_bf<<<1536, 256, 0, stream>>>(Whh, whhb, 393216);
  gather_e<<<2048, 128, 0, stream>>>(tgt, emb, eall);
  init_h<<<64, 256, 0, stream>>>(eh, hf, bar);

  gemm_bt<1, true, true><<<dim3(8, 16), 256, 0, stream>>>(eo, 1024, Wk, 1024, kproj, nullptr, 1024, 1024);
  gemm_bt<1, false, true><<<dim3(24, 16), 256, 0, stream>>>(eall, 1024, Wih, 2048, ge, bih, 1024, 3072);
  gemm_bt<3, true, true><<<dim3(24, 16), 256, 0, stream>>>(eo, 1024, Wih + 1024, 2048, Pt, nullptr, 1024, 3072);

  RP rp;
  rp.Wc = wqb; rp.kproj = kproj; rp.Pt = Pt; rp.ge = ge;
  rp.bhh = bhh; rp.vatt = vatt;
  rp.q = q; rp.gh = gh; rp.scores = sc; rp.hf = hf;
  rp.hseq = hseq; rp.outT = outT; rp.attw = attw;
  rp.bar = bar;
  void* kargs[] = { (void*)&rp };
  hipLaunchCooperativeKernel((void*)rec_kernel, dim3(256), dim3(256), kargs, 0, stream);

  gemm_bt<2, false, true><<<dim3(250, 16), 256, 0, stream>>>(hseq, 1024, Wout, 1024, out, bout, 1024, 32000);
  lse_kernel<<<2048, 256, 0, stream>>>(out, lse);
  fixup_kernel<<<64000, 256, 0, stream>>>(out, lse);
}

// Round 3
// 4004.087 us; speedup vs baseline: 3.2441x; 1.0668x over previous
//
#include <hip/hip_runtime.h>

typedef unsigned short u16;
using f32x4  = __attribute__((ext_vector_type(4))) float;
using bf16x8 = __attribute__((ext_vector_type(8))) __bf16;

// ---------- helpers ----------
__device__ __forceinline__ float bf2f(u16 s){ return __builtin_bit_cast(float, (unsigned)s << 16); }
__device__ __forceinline__ float bflo(unsigned u){ return __builtin_bit_cast(float, u << 16); }
__device__ __forceinline__ float bfhi(unsigned u){ return __builtin_bit_cast(float, u & 0xffff0000u); }
__device__ __forceinline__ u16 f2bf(float f){
  unsigned u = __builtin_bit_cast(unsigned, f);
  unsigned r = u + 0x7fffu + ((u >> 16) & 1u);
  return (u16)(r >> 16);
}
__device__ __forceinline__ unsigned pk2(float x, float y){
  unsigned ux = __builtin_bit_cast(unsigned, x) + 0x8000u;
  unsigned uy = __builtin_bit_cast(unsigned, y) + 0x8000u;
  return (ux >> 16) | (uy & 0xffff0000u);
}
__device__ __forceinline__ float tanh_f(float x){ float e = __expf(2.f*x); return 1.f - 2.f/(e + 1.f); }
__device__ __forceinline__ float sigm(float x){ return 1.f/(1.f + __expf(-x)); }
__device__ __forceinline__ f32x4 mfma16(bf16x8 a, bf16x8 b, f32x4 c){
  return __builtin_amdgcn_mfma_f32_16x16x32_bf16(a, b, c, 0, 0, 0);
}
__device__ __forceinline__ bf16x8 ldg8(const u16* p){
  return __builtin_bit_cast(bf16x8, *(const uint4*)p);
}
__device__ __forceinline__ bf16x8 cvt8(const float* p){
  float4 a = *(const float4*)p, b = *(const float4*)(p + 4);
  uint4 r; r.x = pk2(a.x, a.y); r.y = pk2(a.z, a.w); r.z = pk2(b.x, b.y); r.w = pk2(b.z, b.w);
  return __builtin_bit_cast(bf16x8, r);
}
__device__ __forceinline__ void gld(const void* g, void* l){
  __builtin_amdgcn_global_load_lds(
      (const __attribute__((address_space(1))) void*)g,
      (__attribute__((address_space(3))) void*)l, 16, 0, 0);
}

// coherent (MALL-level) scalar access: bypasses non-coherent per-XCD L2,
// so cross-block data is visible WITHOUT any L2 writeback/invalidate fences.
__device__ __forceinline__ float coh_ld(const float* p){
  return __hip_atomic_load(p, __ATOMIC_RELAXED, __HIP_MEMORY_SCOPE_AGENT);
}
__device__ __forceinline__ void coh_st(float* p, float v){
  __hip_atomic_store(p, v, __ATOMIC_RELAXED, __HIP_MEMORY_SCOPE_AGENT);
}

// ---------- 128x128 bf16-MFMA GEMM with fp32-or-bf16 operands:
//            C[m,n] = sum_k A[m,k]*B[n,k] (+bias[n]) ----------
template<int EPI, bool AF32, bool BF32>
__global__ __launch_bounds__(256) void gemm_bt(
    const void* __restrict__ Av, int lda,
    const void* __restrict__ Bv, int ldb,
    void* __restrict__ Cv, const float* __restrict__ bias,
    int K, int N)
{
  constexpr int ABYTES = AF32 ? 16384 : 8192;
  constexpr int BBYTES = BF32 ? 16384 : 8192;
  __shared__ __align__(16) unsigned char lsA[ABYTES];
  __shared__ __align__(16) unsigned char lsB[BBYTES];
  const int tid = threadIdx.x;
  const int wv = tid >> 6, l = tid & 63;
  const int m0 = blockIdx.y * 128, n0 = blockIdx.x * 128;
  const int wm = wv & 1, wn = wv >> 1;
  const f32x4 vzero = {0.f, 0.f, 0.f, 0.f};
  f32x4 acc[4][4];
#pragma unroll
  for (int i = 0; i < 4; ++i)
#pragma unroll
    for (int j = 0; j < 4; ++j) acc[i][j] = vzero;

  const float* gAf[4]; const u16* gAh[2]; void* dA[4];
  const float* gBf[4]; const u16* gBh[2]; void* dB[4];
  if constexpr (AF32){
    const float* A = (const float*)Av;
#pragma unroll
    for (int i = 0; i < 4; ++i){
      int e = (wv*4 + i)*64 + l;
      int kc = e >> 8, r = (e >> 1) & 127, h4 = (e & 1)*4;
      gAf[i] = A + (size_t)(m0 + r)*lda + kc*8 + h4;
      dA[i] = lsA + (wv*4 + i)*1024;
    }
  } else {
    const u16* A = (const u16*)Av;
#pragma unroll
    for (int i = 0; i < 2; ++i){
      int e = (wv*2 + i)*64 + l;
      int kc = e >> 7, r = e & 127;
      gAh[i] = A + (size_t)(m0 + r)*lda + kc*8;
      dA[i] = lsA + (wv*2 + i)*1024;
    }
  }
  if constexpr (BF32){
    const float* B = (const float*)Bv;
#pragma unroll
    for (int i = 0; i < 4; ++i){
      int e = (wv*4 + i)*64 + l;
      int kc = e >> 8, r = (e >> 1) & 127, h4 = (e & 1)*4;
      gBf[i] = B + (size_t)(n0 + r)*ldb + kc*8 + h4;
      dB[i] = lsB + (wv*4 + i)*1024;
    }
  } else {
    const u16* B = (const u16*)Bv;
#pragma unroll
    for (int i = 0; i < 2; ++i){
      int e = (wv*2 + i)*64 + l;
      int kc = e >> 7, r = e & 127;
      gBh[i] = B + (size_t)(n0 + r)*ldb + kc*8;
      dB[i] = lsB + (wv*2 + i)*1024;
    }
  }
  const int kq = l >> 4, li = l & 15;

  for (int k0 = 0; k0 < K; k0 += 32){
    __syncthreads();
    if constexpr (AF32){
#pragma unroll
      for (int i = 0; i < 4; ++i) gld(gAf[i] + k0, dA[i]);
    } else {
#pragma unroll
      for (int i = 0; i < 2; ++i) gld(gAh[i] + k0, dA[i]);
    }
    if constexpr (BF32){
#pragma unroll
      for (int i = 0; i < 4; ++i) gld(gBf[i] + k0, dB[i]);
    } else {
#pragma unroll
      for (int i = 0; i < 2; ++i) gld(gBh[i] + k0, dB[i]);
    }
    __syncthreads();
    bf16x8 aF[4], bF[4];
#pragma unroll
    for (int mi = 0; mi < 4; ++mi){
      int idx = kq*128 + wm*64 + mi*16 + li;
      if constexpr (AF32) aF[mi] = cvt8((const float*)lsA + idx*8);
      else                aF[mi] = ldg8((const u16*)lsA + idx*8);
    }
#pragma unroll
    for (int ni = 0; ni < 4; ++ni){
      int idx = kq*128 + wn*64 + ni*16 + li;
      if constexpr (BF32) bF[ni] = cvt8((const float*)lsB + idx*8);
      else                bF[ni] = ldg8((const u16*)lsB + idx*8);
    }
#pragma unroll
    for (int mi = 0; mi < 4; ++mi)
#pragma unroll
      for (int ni = 0; ni < 4; ++ni)
        acc[mi][ni] = mfma16(aF[mi], bF[ni], acc[mi][ni]);
  }

#pragma unroll
  for (int mi = 0; mi < 4; ++mi){
    const int mloc = wm*64 + mi*16 + kq*4;
#pragma unroll
    for (int ni = 0; ni < 4; ++ni){
      const int col = n0 + wn*64 + ni*16 + li;
      f32x4 v = acc[mi][ni];
      if constexpr (EPI == 1){
        float bb = bias ? bias[col] : 0.f;
        u16* C = (u16*)Cv;
#pragma unroll
        for (int r = 0; r < 4; ++r)
          C[(size_t)(m0 + mloc + r)*N + col] = f2bf(v[r] + bb);
      } else if constexpr (EPI == 2){
        float bb = bias[col];
        float* C = (float*)Cv;
#pragma unroll
        for (int r = 0; r < 4; ++r){
          int m = m0 + mloc + r;
          int orow = (m & 15)*128 + (m >> 4);
          C[(size_t)orow*N + col] = v[r] + bb;
        }
      } else { // EPI == 3
        u16* C = (u16*)Cv;
        int m = m0 + mloc;
        int b = m >> 7, s = m & 127;
        unsigned w0 = (unsigned)f2bf(v[0]) | ((unsigned)f2bf(v[1]) << 16);
        unsigned w1 = (unsigned)f2bf(v[2]) | ((unsigned)f2bf(v[3]) << 16);
        uint2 pk; pk.x = w0; pk.y = w1;
        *(uint2*)(C + ((size_t)b*N + col)*128 + s) = pk;
      }
    }
  }
}

// ---------- rearranged weight build: Wc2 row (ic*256 + lr) =
//   lr <  64 : Wq row  ic*64 + lr
//   lr >= 64 : Whh row gate*1024 + ic*64 + i, gate=(lr-64)>>6, i=(lr-64)&63
__global__ void cast_w2(const float* __restrict__ Wq, const float* __restrict__ Whh, u16* __restrict__ Wc2){
  int r2 = blockIdx.x;          // 0..4095
  int ic = r2 >> 8, lr = r2 & 255;
  const float* src;
  if (lr < 64) src = Wq + (size_t)(ic*64 + lr)*1024;
  else { int gate = (lr - 64) >> 6, i = (lr - 64) & 63; src = Whh + (size_t)(gate*1024 + ic*64 + i)*1024; }
  const float4* s4 = (const float4*)src + threadIdx.x*2;
  float4 a = s4[0], c = s4[1];
  uint4 r; r.x = pk2(a.x, a.y); r.y = pk2(a.z, a.w); r.z = pk2(c.x, c.y); r.w = pk2(c.z, c.w);
  ((uint4*)(Wc2 + (size_t)r2*1024))[threadIdx.x] = r;
}

// ---------- embedding gather + cast ----------
__global__ void gather_e(const int* __restrict__ tgt, const float* __restrict__ emb, u16* __restrict__ eall){
  int p = blockIdx.x;           // t*16 + b
  int t = p >> 4, b = p & 15;
  int tok = (t == 0) ? 1 : tgt[b*128 + (t - 1)];
  const float4* src = (const float4*)(emb + (size_t)tok*1024) + threadIdx.x*2;
  float4 a = src[0], c = src[1];
  uint4 r; r.x = pk2(a.x, a.y); r.y = pk2(a.z, a.w); r.z = pk2(c.x, c.y); r.w = pk2(c.z, c.w);
  ((uint4*)(eall + (size_t)p*1024))[threadIdx.x] = r;
}

// init h (fp32) + zero the group-barrier counters (must re-zero every launch)
__global__ void init_h(const float* __restrict__ eh, float* __restrict__ hf, int* __restrict__ bar){
  int i = blockIdx.x*256 + threadIdx.x;
  if (i < 1024) bar[i] = 0;
  hf[i] = eh[i];
}

// ---------- recurrent cooperative kernel: 16 groups x 16 blocks, 2 barriers/step ----------
struct RP {
  const u16 *Wc2, *kproj, *Pt, *ge;
  const float *bhh, *vatt;
  float *psc, *hf;
  u16 *hseq;
  float *outT, *attw;
  int *bar;
};

// 16-block fence-free barrier (proven round 2): cross-block data moves via
// coh_st/coh_ld (MALL), per-XCD L2 stays untouched and weight-resident.
__device__ __forceinline__ void gbar(int* cnt, int target){
  __syncthreads();
  if (threadIdx.x == 0){
    __hip_atomic_fetch_add(cnt, 1, __ATOMIC_RELAXED, __HIP_MEMORY_SCOPE_AGENT);
    while (__hip_atomic_load(cnt, __ATOMIC_RELAXED, __HIP_MEMORY_SCOPE_AGENT) < target)
      __builtin_amdgcn_s_sleep(1);
  }
  __syncthreads();
}

__global__ __launch_bounds__(256) void rec_kernel(RP p){
  __shared__ float hshm[1024];
  __shared__ float qv[64];     // this block's q slice   (h-local)
  __shared__ float ghv[192];   // this block's gh slice  (h-local, never leaves block)
  __shared__ float vv[64];     // v_att slice
  __shared__ float sraw[128];
  __shared__ float wf[128];
  __shared__ float gcv[192];
  const int tid = threadIdx.x;
  const int blk = blockIdx.x;
  const int b = blk >> 4, ic = blk & 15;   // group = batch b, member ic; XCD = ic%8
  const int wv = tid >> 6, l = tid & 63;
  int* cnt = p.bar + b*32;
  int target = 0;

  // fixed GEMV row (rearranged weights): r2 = ic*256 + tid
  const u16* wr = p.Wc2 + ((size_t)(ic*256 + tid))*1024;
  float badd = 0.f;
  if (tid >= 64){
    int gate = (tid - 64) >> 6, i = (tid - 64) & 63;
    badd = p.bhh[gate*1024 + ic*64 + i];
  }
  if (tid < 64) vv[tid] = p.vatt[ic*64 + tid];

  // partial-score assignment: pair (s = tid>>1, half = tid&1), 32 h each
  const int s_pair = tid >> 1, half = tid & 1;
  const u16* kbase = p.kproj + ((size_t)(b*128 + s_pair))*1024 + ic*64 + half*32;
  float* pscw = p.psc + (b*16 + ic)*128 + s_pair;

  // persistent h slice owned by this block: i = ic*64 + tid (tid < 64)
  float hreg = (tid < 64) ? p.hf[b*1024 + ic*64 + tid] : 0.f;

  for (int t = 0; t < 128; ++t){
    // ---- segment 1: q/gh GEMV + partial scores ----
    {
      const float* hfb = p.hf + b*1024 + tid*4;
      float4 hv;
      hv.x = coh_ld(hfb + 0); hv.y = coh_ld(hfb + 1);
      hv.z = coh_ld(hfb + 2); hv.w = coh_ld(hfb + 3);
      ((float4*)hshm)[tid] = hv;
    }
    __syncthreads();
    {
      float a0 = 0.f, a1 = 0.f, a2 = 0.f, a3 = 0.f;
#pragma unroll 8
      for (int k0 = 0; k0 < 1024; k0 += 8){
        uint4 u = *(const uint4*)(wr + k0);
        a0 += hshm[k0+0]*bflo(u.x) + hshm[k0+1]*bfhi(u.x);
        a1 += hshm[k0+2]*bflo(u.y) + hshm[k0+3]*bfhi(u.y);
        a2 += hshm[k0+4]*bflo(u.z) + hshm[k0+5]*bfhi(u.z);
        a3 += hshm[k0+6]*bflo(u.w) + hshm[k0+7]*bfhi(u.w);
      }
      float r = (a0 + a1) + (a2 + a3) + badd;
      if (tid < 64) qv[tid] = r; else ghv[tid - 64] = r;
    }
    __syncthreads();
    {
      float acc = 0.f;
#pragma unroll
      for (int c = 0; c < 4; ++c){
        uint4 u = *(const uint4*)(kbase + c*8);
        int j = half*32 + c*8;
        acc += vv[j+0]*tanh_f(qv[j+0] + bflo(u.x)) + vv[j+1]*tanh_f(qv[j+1] + bfhi(u.x));
        acc += vv[j+2]*tanh_f(qv[j+2] + bflo(u.y)) + vv[j+3]*tanh_f(qv[j+3] + bfhi(u.y));
        acc += vv[j+4]*tanh_f(qv[j+4] + bflo(u.z)) + vv[j+5]*tanh_f(qv[j+5] + bfhi(u.z));
        acc += vv[j+6]*tanh_f(qv[j+6] + bflo(u.w)) + vv[j+7]*tanh_f(qv[j+7] + bfhi(u.w));
      }
      acc += __shfl_xor(acc, 1);
      if (half == 0) coh_st(pscw, acc);
    }
    target += 16; gbar(cnt, target);

    // ---- segment 2: score reduce + softmax + ctx (Pt) + GRU update ----
    if (tid < 128){
      const float* pr = p.psc + b*2048 + tid;
      float s0 = 0.f;
#pragma unroll
      for (int j = 0; j < 16; ++j) s0 += coh_ld(pr + j*128);
      sraw[tid] = s0;
    }
    __syncthreads();
    if (wv == 0){
      float x0 = sraw[l], x1 = sraw[64 + l];
      float m = fmaxf(x0, x1);
#pragma unroll
      for (int o = 32; o; o >>= 1) m = fmaxf(m, __shfl_xor(m, o));
      float e0 = __expf(x0 - m), e1 = __expf(x1 - m);
      float sm = e0 + e1;
#pragma unroll
      for (int o = 32; o; o >>= 1) sm += __shfl_xor(sm, o);
      float inv = 1.f / sm;
      wf[l] = e0*inv; wf[64 + l] = e1*inv;
    }
    __syncthreads();
    if (tid < 192){
      int gate = tid >> 6, ii = tid & 63;
      int j = gate*1024 + ic*64 + ii;
      const uint4* pr = (const uint4*)(p.Pt + ((size_t)(b*3072 + j))*128);
      float acc = 0.f;
#pragma unroll
      for (int c = 0; c < 16; ++c){
        uint4 u = pr[c];
        const float* w8 = &wf[c*8];
        acc += w8[0]*bflo(u.x) + w8[1]*bfhi(u.x)
             + w8[2]*bflo(u.y) + w8[3]*bfhi(u.y)
             + w8[4]*bflo(u.z) + w8[5]*bfhi(u.z)
             + w8[6]*bflo(u.w) + w8[7]*bfhi(u.w);
      }
      gcv[tid] = acc;
    }
    __syncthreads();
    if (tid < 64){
      int i = ic*64 + tid;
      size_t mrow = (size_t)(t*16 + b);
      const u16* gep = p.ge + mrow*3072;
      float ger = bf2f(gep[i]), gez = bf2f(gep[i + 1024]), gen = bf2f(gep[i + 2048]);
      float ghr = ghv[tid], ghz = ghv[64 + tid], ghn = ghv[128 + tid];
      float rg = sigm(ger + gcv[tid] + ghr);
      float z  = sigm(gez + gcv[64 + tid] + ghz);
      float n  = tanh_f(gen + gcv[128 + tid] + rg*ghn);
      float hn = (1.f - z)*n + z*hreg;
      hreg = hn;
      coh_st(p.hf + b*1024 + i, hn);
      p.hseq[mrow*1024 + i] = f2bf(hn);
      if (t == 127) p.outT[b*1024 + i] = hn;
    }
    if (ic == 0 && tid < 128){
      p.attw[((size_t)(b*128 + t))*128 + tid] = wf[tid];
    }
    target += 16; gbar(cnt, target);
  }
}

// ---------- logsumexp over V per output row, then in-place fixup ----------
__global__ __launch_bounds__(256) void lse_kernel(const float* __restrict__ outp, float* __restrict__ lse){
  __shared__ float rm[256], rs[256];
  int r = blockIdx.x, tid = threadIdx.x;
  const float4* rp = (const float4*)(outp + (size_t)r*32000);
  float m = -3.0e38f, s = 0.f;
  for (int v = tid; v < 8000; v += 256){
    float4 x = rp[v];
    float mx = fmaxf(fmaxf(x.x, x.y), fmaxf(x.z, x.w));
    if (mx > m){ s *= __expf(m - mx); m = mx; }
    s += __expf(x.x - m) + __expf(x.y - m) + __expf(x.z - m) + __expf(x.w - m);
  }
  rm[tid] = m; rs[tid] = s;
  __syncthreads();
  for (int o = 128; o; o >>= 1){
    if (tid < o){
      float m2 = rm[tid + o], s2 = rs[tid + o], m1 = rm[tid], s1 = rs[tid];
      float M = fmaxf(m1, m2);
      rs[tid] = s1*__expf(m1 - M) + s2*__expf(m2 - M);
      rm[tid] = M;
    }
    __syncthreads();
  }
  if (tid == 0) lse[r] = rm[0] + __logf(rs[0]);
}

__global__ __launch_bounds__(256) void fixup_kernel(float* __restrict__ outp, const float* __restrict__ lse){
  int idx = blockIdx.x*256 + threadIdx.x;
  int r = idx / 8000;
  float L = lse[r];
  float4* p4 = (float4*)outp;
  float4 u = p4[idx];
  u.x -= L; u.y -= L; u.z -= L; u.w -= L;
  p4[idx] = u;
}

// ---------- host ----------
extern "C" void kernel_launch(void* const* d_in, const int* in_sizes, int n_in,
                              void* d_out, int out_size, void* d_ws, size_t ws_size,
                              hipStream_t stream) {
  (void)in_sizes; (void)n_in; (void)out_size; (void)ws_size;
  const float* eo   = (const float*)d_in[0];
  const float* eh   = (const float*)d_in[1];
  const int*   tgt  = (const int*)d_in[2];
  const float* emb  = (const float*)d_in[3];
  const float* Wq   = (const float*)d_in[4];
  const float* Wk   = (const float*)d_in[5];
  const float* vatt = (const float*)d_in[6];
  const float* Wih  = (const float*)d_in[7];
  const float* Whh  = (const float*)d_in[8];
  const float* bih  = (const float*)d_in[9];
  const float* bhh  = (const float*)d_in[10];
  const float* Wout = (const float*)d_in[11];
  const float* bout = (const float*)d_in[12];
  float* out = (float*)d_out;

  char* ws = (char*)d_ws;
  u16*  kproj = (u16*) (ws + 0);          //  4 MiB  [16*128][1024] bf16
  u16*  ge    = (u16*) (ws + 4194304);    // 12 MiB  [128*16][3072] bf16 (incl b_ih)
  u16*  Pt    = (u16*) (ws + 16777216);   // 12 MiB  [16][3072][128] bf16
  u16*  eall  = (u16*) (ws + 29360128);   //  4 MiB  [128*16][1024] bf16
  u16*  hseq  = (u16*) (ws + 33554432);   //  4 MiB  [128*16][1024] bf16
  u16*  wc2   = (u16*) (ws + 37748736);   //  8 MiB  rearranged [4096][1024] bf16
  float* hf   = (float*)(ws + 46137344);  // 64 KiB  [16][1024] f32
  int*  bar   = (int*)  (ws + 46202880);  // 32 KiB  group-barrier counters
  float* psc  = (float*)(ws + 46235648);  // 128 KiB [16][16][128] partial scores
  float* lse  = (float*)(ws + 46505984);  //  8 KiB

  float* outT = out + 65536000;
  float* attw = out + 65552384;

  cast_w2<<<4096, 128, 0, stream>>>(Wq, Whh, wc2);
  gather_e<<<2048, 128, 0, stream>>>(tgt, emb, eall);
  init_h<<<64, 256, 0, stream>>>(eh, hf, bar);

  gemm_bt<1, true, true><<<dim3(8, 16), 256, 0, stream>>>(eo, 1024, Wk, 1024, kproj, nullptr, 1024, 1024);
  gemm_bt<1, false, true><<<dim3(24, 16), 256, 0, stream>>>(eall, 1024, Wih, 2048, ge, bih, 1024, 3072);
  gemm_bt<3, true, true><<<dim3(24, 16), 256, 0, stream>>>(eo, 1024, Wih + 1024, 2048, Pt, nullptr, 1024, 3072);

  RP rp;
  rp.Wc2 = wc2; rp.kproj = kproj; rp.Pt = Pt; rp.ge = ge;
  rp.bhh = bhh; rp.vatt = vatt;
  rp.psc = psc; rp.hf = hf;
  rp.hseq = hseq; rp.outT = outT; rp.attw = attw;
  rp.bar = bar;
  void* kargs[] = { (void*)&rp };
  hipLaunchCooperativeKernel((void*)rec_kernel, dim3(256), dim3(256), kargs, 0, stream);

  gemm_bt<2, false, true><<<dim3(250, 16), 256, 0, stream>>>(hseq, 1024, Wout, 1024, out, bout, 1024, 32000);
  lse_kernel<<<2048, 256, 0, stream>>>(out, lse);
  fixup_kernel<<<64000, 256, 0, stream>>>(out, lse);
}

// Round 5
// 3763.448 us; speedup vs baseline: 3.4516x; 1.0639x over previous
//
#include <hip/hip_runtime.h>

typedef unsigned short u16;
using f32x4  = __attribute__((ext_vector_type(4))) float;
using bf16x8 = __attribute__((ext_vector_type(8))) __bf16;

// ---------- helpers ----------
__device__ __forceinline__ float bf2f(u16 s){ return __builtin_bit_cast(float, (unsigned)s << 16); }
__device__ __forceinline__ float bflo(unsigned u){ return __builtin_bit_cast(float, u << 16); }
__device__ __forceinline__ float bfhi(unsigned u){ return __builtin_bit_cast(float, u & 0xffff0000u); }
__device__ __forceinline__ u16 f2bf(float f){
  unsigned u = __builtin_bit_cast(unsigned, f);
  unsigned r = u + 0x7fffu + ((u >> 16) & 1u);
  return (u16)(r >> 16);
}
__device__ __forceinline__ unsigned pk2(float x, float y){
  unsigned ux = __builtin_bit_cast(unsigned, x) + 0x8000u;
  unsigned uy = __builtin_bit_cast(unsigned, y) + 0x8000u;
  return (ux >> 16) | (uy & 0xffff0000u);
}
__device__ __forceinline__ float tanh_f(float x){ float e = __expf(2.f*x); return 1.f - 2.f/(e + 1.f); }
__device__ __forceinline__ float sigm(float x){ return 1.f/(1.f + __expf(-x)); }
__device__ __forceinline__ f32x4 mfma16(bf16x8 a, bf16x8 b, f32x4 c){
  return __builtin_amdgcn_mfma_f32_16x16x32_bf16(a, b, c, 0, 0, 0);
}
__device__ __forceinline__ bf16x8 ldg8(const u16* p){
  return __builtin_bit_cast(bf16x8, *(const uint4*)p);
}
__device__ __forceinline__ bf16x8 cvt8(const float* p){
  float4 a = *(const float4*)p, b = *(const float4*)(p + 4);
  uint4 r; r.x = pk2(a.x, a.y); r.y = pk2(a.z, a.w); r.z = pk2(b.x, b.y); r.w = pk2(b.z, b.w);
  return __builtin_bit_cast(bf16x8, r);
}
__device__ __forceinline__ void gld(const void* g, void* l){
  __builtin_amdgcn_global_load_lds(
      (const __attribute__((address_space(1))) void*)g,
      (__attribute__((address_space(3))) void*)l, 16, 0, 0);
}

// coherent (MALL-level) scalar access: bypasses non-coherent per-XCD L2.
// Fence-free cross-XCD exchange with these proven rounds 1-3.
__device__ __forceinline__ float coh_ld(const float* p){
  return __hip_atomic_load(p, __ATOMIC_RELAXED, __HIP_MEMORY_SCOPE_AGENT);
}
__device__ __forceinline__ void coh_st(float* p, float v){
  __hip_atomic_store(p, v, __ATOMIC_RELAXED, __HIP_MEMORY_SCOPE_AGENT);
}

// ---------- 128x128 bf16-MFMA GEMM with fp32-or-bf16 operands:
//            C[m,n] = sum_k A[m,k]*B[n,k] (+bias[n]) ----------
template<int EPI, bool AF32, bool BF32>
__global__ __launch_bounds__(256) void gemm_bt(
    const void* __restrict__ Av, int lda,
    const void* __restrict__ Bv, int ldb,
    void* __restrict__ Cv, const float* __restrict__ bias,
    int K, int N)
{
  constexpr int ABYTES = AF32 ? 16384 : 8192;
  constexpr int BBYTES = BF32 ? 16384 : 8192;
  __shared__ __align__(16) unsigned char lsA[ABYTES];
  __shared__ __align__(16) unsigned char lsB[BBYTES];
  const int tid = threadIdx.x;
  const int wv = tid >> 6, l = tid & 63;
  const int m0 = blockIdx.y * 128, n0 = blockIdx.x * 128;
  const int wm = wv & 1, wn = wv >> 1;
  const f32x4 vzero = {0.f, 0.f, 0.f, 0.f};
  f32x4 acc[4][4];
#pragma unroll
  for (int i = 0; i < 4; ++i)
#pragma unroll
    for (int j = 0; j < 4; ++j) acc[i][j] = vzero;

  const float* gAf[4]; const u16* gAh[2]; void* dA[4];
  const float* gBf[4]; const u16* gBh[2]; void* dB[4];
  if constexpr (AF32){
    const float* A = (const float*)Av;
#pragma unroll
    for (int i = 0; i < 4; ++i){
      int e = (wv*4 + i)*64 + l;
      int kc = e >> 8, r = (e >> 1) & 127, h4 = (e & 1)*4;
      gAf[i] = A + (size_t)(m0 + r)*lda + kc*8 + h4;
      dA[i] = lsA + (wv*4 + i)*1024;
    }
  } else {
    const u16* A = (const u16*)Av;
#pragma unroll
    for (int i = 0; i < 2; ++i){
      int e = (wv*2 + i)*64 + l;
      int kc = e >> 7, r = e & 127;
      gAh[i] = A + (size_t)(m0 + r)*lda + kc*8;
      dA[i] = lsA + (wv*2 + i)*1024;
    }
  }
  if constexpr (BF32){
    const float* B = (const float*)Bv;
#pragma unroll
    for (int i = 0; i < 4; ++i){
      int e = (wv*4 + i)*64 + l;
      int kc = e >> 8, r = (e >> 1) & 127, h4 = (e & 1)*4;
      gBf[i] = B + (size_t)(n0 + r)*ldb + kc*8 + h4;
      dB[i] = lsB + (wv*4 + i)*1024;
    }
  } else {
    const u16* B = (const u16*)Bv;
#pragma unroll
    for (int i = 0; i < 2; ++i){
      int e = (wv*2 + i)*64 + l;
      int kc = e >> 7, r = e & 127;
      gBh[i] = B + (size_t)(n0 + r)*ldb + kc*8;
      dB[i] = lsB + (wv*2 + i)*1024;
    }
  }
  const int kq = l >> 4, li = l & 15;

  for (int k0 = 0; k0 < K; k0 += 32){
    __syncthreads();
    if constexpr (AF32){
#pragma unroll
      for (int i = 0; i < 4; ++i) gld(gAf[i] + k0, dA[i]);
    } else {
#pragma unroll
      for (int i = 0; i < 2; ++i) gld(gAh[i] + k0, dA[i]);
    }
    if constexpr (BF32){
#pragma unroll
      for (int i = 0; i < 4; ++i) gld(gBf[i] + k0, dB[i]);
    } else {
#pragma unroll
      for (int i = 0; i < 2; ++i) gld(gBh[i] + k0, dB[i]);
    }
    __syncthreads();
    bf16x8 aF[4], bF[4];
#pragma unroll
    for (int mi = 0; mi < 4; ++mi){
      int idx = kq*128 + wm*64 + mi*16 + li;
      if constexpr (AF32) aF[mi] = cvt8((const float*)lsA + idx*8);
      else                aF[mi] = ldg8((const u16*)lsA + idx*8);
    }
#pragma unroll
    for (int ni = 0; ni < 4; ++ni){
      int idx = kq*128 + wn*64 + ni*16 + li;
      if constexpr (BF32) bF[ni] = cvt8((const float*)lsB + idx*8);
      else                bF[ni] = ldg8((const u16*)lsB + idx*8);
    }
#pragma unroll
    for (int mi = 0; mi < 4; ++mi)
#pragma unroll
      for (int ni = 0; ni < 4; ++ni)
        acc[mi][ni] = mfma16(aF[mi], bF[ni], acc[mi][ni]);
  }

#pragma unroll
  for (int mi = 0; mi < 4; ++mi){
    const int mloc = wm*64 + mi*16 + kq*4;
#pragma unroll
    for (int ni = 0; ni < 4; ++ni){
      const int col = n0 + wn*64 + ni*16 + li;
      f32x4 v = acc[mi][ni];
      if constexpr (EPI == 1){
        float bb = bias ? bias[col] : 0.f;
        u16* C = (u16*)Cv;
#pragma unroll
        for (int r = 0; r < 4; ++r)
          C[(size_t)(m0 + mloc + r)*N + col] = f2bf(v[r] + bb);
      } else if constexpr (EPI == 2){
        float bb = bias[col];
        float* C = (float*)Cv;
#pragma unroll
        for (int r = 0; r < 4; ++r){
          int m = m0 + mloc + r;
          int orow = (m & 15)*128 + (m >> 4);
          C[(size_t)orow*N + col] = v[r] + bb;
        }
      } else { // EPI == 3
        u16* C = (u16*)Cv;
        int m = m0 + mloc;
        int b = m >> 7, s = m & 127;
        unsigned w0 = (unsigned)f2bf(v[0]) | ((unsigned)f2bf(v[1]) << 16);
        unsigned w1 = (unsigned)f2bf(v[2]) | ((unsigned)f2bf(v[3]) << 16);
        uint2 pk; pk.x = w0; pk.y = w1;
        *(uint2*)(C + ((size_t)b*N + col)*128 + s) = pk;
      }
    }
  }
}

// ---------- rearranged weight build: Wc2 row (ic*256 + lr) =
//   lr <  64 : Wq row  ic*64 + lr
//   lr >= 64 : Whh row gate*1024 + ic*64 + i, gate=(lr-64)>>6, i=(lr-64)&63
__global__ void cast_w2(const float* __restrict__ Wq, const float* __restrict__ Whh, u16* __restrict__ Wc2){
  int r2 = blockIdx.x;          // 0..4095
  int ic = r2 >> 8, lr = r2 & 255;
  const float* src;
  if (lr < 64) src = Wq + (size_t)(ic*64 + lr)*1024;
  else { int gate = (lr - 64) >> 6, i = (lr - 64) & 63; src = Whh + (size_t)(gate*1024 + ic*64 + i)*1024; }
  const float4* s4 = (const float4*)src + threadIdx.x*2;
  float4 a = s4[0], c = s4[1];
  uint4 r; r.x = pk2(a.x, a.y); r.y = pk2(a.z, a.w); r.z = pk2(c.x, c.y); r.w = pk2(c.z, c.w);
  ((uint4*)(Wc2 + (size_t)r2*1024))[threadIdx.x] = r;
}

// ---------- embedding gather + cast ----------
__global__ void gather_e(const int* __restrict__ tgt, const float* __restrict__ emb, u16* __restrict__ eall){
  int p = blockIdx.x;           // t*16 + b
  int t = p >> 4, b = p & 15;
  int tok = (t == 0) ? 1 : tgt[b*128 + (t - 1)];
  const float4* src = (const float4*)(emb + (size_t)tok*1024) + threadIdx.x*2;
  float4 a = src[0], c = src[1];
  uint4 r; r.x = pk2(a.x, a.y); r.y = pk2(a.z, a.w); r.z = pk2(c.x, c.y); r.w = pk2(c.z, c.w);
  ((uint4*)(eall + (size_t)p*1024))[threadIdx.x] = r;
}

// init h (fp32) + zero the group-barrier counters (must re-zero every launch)
__global__ void init_h(const float* __restrict__ eh, float* __restrict__ hf, int* __restrict__ bar){
  int i = blockIdx.x*256 + threadIdx.x;
  if (i < 1024) bar[i] = 0;
  hf[i] = eh[i];
}

// ---------- recurrent cooperative kernel: 16 groups x 16 blocks x 512 threads ----------
struct RP {
  const u16 *Wc2, *kproj, *Pt, *ge;
  const float *bhh, *vatt;
  float *psc, *hf;
  u16 *hseq;
  float *outT, *attw;
  int *bar;
};

// fence-free group barrier (proven rounds 2-3)
__device__ __forceinline__ void gbar(int* cnt, int target){
  __syncthreads();
  if (threadIdx.x == 0){
    __hip_atomic_fetch_add(cnt, 1, __ATOMIC_RELAXED, __HIP_MEMORY_SCOPE_AGENT);
    while (__hip_atomic_load(cnt, __ATOMIC_RELAXED, __HIP_MEMORY_SCOPE_AGENT) < target)
      __builtin_amdgcn_s_sleep(1);
  }
  __syncthreads();
}

__global__ __launch_bounds__(512) void rec_kernel(RP p){
  __shared__ float hshm[1024];
  __shared__ float qv[64];     // block's q slice   (64 h)
  __shared__ float ghv[192];   // block's gh slice  (3 gates x 64 h, block-local)
  __shared__ float vv[64];
  __shared__ float sraw[128];
  __shared__ float wf[128];
  __shared__ float gcv[192];
  const int tid = threadIdx.x;
  const int blk = blockIdx.x;
  const int b = blk >> 4, ic = blk & 15;   // group = batch b (16), member ic (16); XCD = ic%8
  const int wv = tid >> 6, l = tid & 63;
  int* cnt = p.bar + b*64;                 // 256B-strided per-group counter
  int target = 0;

  // GEMV: row lr = tid>>1 (256 rows/block), k-half = tid&1 (512 k each)
  const int lr = tid >> 1, half = tid & 1;
  const u16* wr = p.Wc2 + ((size_t)(ic*256 + lr))*1024 + half*512;
  float badd = 0.f;
  if (lr >= 64){ int gate = (lr - 64) >> 6, i = (lr - 64) & 63; badd = p.bhh[gate*1024 + ic*64 + i]; }
  if (tid < 64) vv[tid] = p.vatt[ic*64 + tid];

  // score partials: s = tid>>2 (128 s), quarter = tid&3 (16 h each of block's 64)
  const int sq = tid >> 2, q4 = tid & 3;
  const u16* kbase = p.kproj + ((size_t)(b*128 + sq))*1024 + ic*64 + q4*16;
  float* pscw = p.psc + ((size_t)(b*128 + sq))*16 + ic;   // psc[b][s][16] contiguous

  // persistent h slice: i = ic*64 + tid (tid < 64)
  float hreg = (tid < 64) ? p.hf[b*1024 + ic*64 + tid] : 0.f;

  for (int t = 0; t < 128; ++t){
    // ---- segment 1: q/gh GEMV + score partials ----
    {
      const float* hfb = p.hf + b*1024 + tid*2;
      float2 hv; hv.x = coh_ld(hfb); hv.y = coh_ld(hfb + 1);
      ((float2*)hshm)[tid] = hv;
    }
    __syncthreads();
    {
      const float* hb = hshm + half*512;
      float a0 = 0.f, a1 = 0.f, a2 = 0.f, a3 = 0.f;
#pragma unroll 8
      for (int k0 = 0; k0 < 512; k0 += 8){
        uint4 u = *(const uint4*)(wr + k0);
        a0 += hb[k0+0]*bflo(u.x) + hb[k0+1]*bfhi(u.x);
        a1 += hb[k0+2]*bflo(u.y) + hb[k0+3]*bfhi(u.y);
        a2 += hb[k0+4]*bflo(u.z) + hb[k0+5]*bfhi(u.z);
        a3 += hb[k0+6]*bflo(u.w) + hb[k0+7]*bfhi(u.w);
      }
      float rsum = (a0 + a1) + (a2 + a3);
      rsum += __shfl_xor(rsum, 1);
      if (half == 0){
        float r = rsum + badd;
        if (lr < 64) qv[lr] = r; else ghv[lr - 64] = r;
      }
    }
    __syncthreads();
    {
      uint4 u0 = *(const uint4*)(kbase);
      uint4 u1 = *(const uint4*)(kbase + 8);
      int j = q4*16;
      float acc = 0.f;
      acc += vv[j+0]*tanh_f(qv[j+0] + bflo(u0.x)) + vv[j+1]*tanh_f(qv[j+1] + bfhi(u0.x));
      acc += vv[j+2]*tanh_f(qv[j+2] + bflo(u0.y)) + vv[j+3]*tanh_f(qv[j+3] + bfhi(u0.y));
      acc += vv[j+4]*tanh_f(qv[j+4] + bflo(u0.z)) + vv[j+5]*tanh_f(qv[j+5] + bfhi(u0.z));
      acc += vv[j+6]*tanh_f(qv[j+6] + bflo(u0.w)) + vv[j+7]*tanh_f(qv[j+7] + bfhi(u0.w));
      acc += vv[j+8]*tanh_f(qv[j+8] + bflo(u1.x)) + vv[j+9]*tanh_f(qv[j+9] + bfhi(u1.x));
      acc += vv[j+10]*tanh_f(qv[j+10] + bflo(u1.y)) + vv[j+11]*tanh_f(qv[j+11] + bfhi(u1.y));
      acc += vv[j+12]*tanh_f(qv[j+12] + bflo(u1.z)) + vv[j+13]*tanh_f(qv[j+13] + bfhi(u1.z));
      acc += vv[j+14]*tanh_f(qv[j+14] + bflo(u1.w)) + vv[j+15]*tanh_f(qv[j+15] + bfhi(u1.w));
      acc += __shfl_xor(acc, 1);
      acc += __shfl_xor(acc, 2);
      if (q4 == 0) coh_st(pscw, acc);
    }
    target += 16; gbar(cnt, target);

    // ---- segment 2: reduce + softmax + ctx (Pt) + GRU ----
    {
      const float* pr = p.psc + ((size_t)(b*128 + sq))*16 + q4*4;
      float s0 = coh_ld(pr) + coh_ld(pr + 1) + coh_ld(pr + 2) + coh_ld(pr + 3);
      s0 += __shfl_xor(s0, 1);
      s0 += __shfl_xor(s0, 2);
      if (q4 == 0) sraw[sq] = s0;
    }
    __syncthreads();
    if (wv == 0){
      float x0 = sraw[l], x1 = sraw[64 + l];
      float m = fmaxf(x0, x1);
#pragma unroll
      for (int o = 32; o; o >>= 1) m = fmaxf(m, __shfl_xor(m, o));
      float e0 = __expf(x0 - m), e1 = __expf(x1 - m);
      float sm = e0 + e1;
#pragma unroll
      for (int o = 32; o; o >>= 1) sm += __shfl_xor(sm, o);
      float inv = 1.f / sm;
      wf[l] = e0*inv; wf[64 + l] = e1*inv;
    }
    __syncthreads();
    if (tid < 384){
      int jj = tid >> 1, hf2 = tid & 1;    // 192 gate-rows, k-split by hf2
      int j = (jj >> 6)*1024 + ic*64 + (jj & 63);
      const uint4* pr2 = (const uint4*)(p.Pt + ((size_t)(b*3072 + j))*128) + hf2*8;
      float acc = 0.f;
#pragma unroll
      for (int c = 0; c < 8; ++c){
        uint4 u = pr2[c];
        const float* w8 = &wf[(hf2*8 + c)*8];
        acc += w8[0]*bflo(u.x) + w8[1]*bfhi(u.x)
             + w8[2]*bflo(u.y) + w8[3]*bfhi(u.y)
             + w8[4]*bflo(u.z) + w8[5]*bfhi(u.z)
             + w8[6]*bflo(u.w) + w8[7]*bfhi(u.w);
      }
      acc += __shfl_xor(acc, 1);
      if (hf2 == 0) gcv[jj] = acc;
    }
    __syncthreads();
    if (tid < 64){
      int i = ic*64 + tid;
      size_t mrow = (size_t)(t*16 + b);
      const u16* gep = p.ge + mrow*3072;
      float ger = bf2f(__builtin_nontemporal_load(gep + i));
      float gez = bf2f(__builtin_nontemporal_load(gep + i + 1024));
      float gen = bf2f(__builtin_nontemporal_load(gep + i + 2048));
      float rg = sigm(ger + gcv[tid] + ghv[tid]);
      float z  = sigm(gez + gcv[64 + tid] + ghv[64 + tid]);
      float n  = tanh_f(gen + gcv[128 + tid] + rg*ghv[128 + tid]);
      float hn = (1.f - z)*n + z*hreg;
      hreg = hn;
      coh_st(p.hf + b*1024 + i, hn);
      __builtin_nontemporal_store(f2bf(hn), p.hseq + mrow*1024 + i);
      if (t == 127) p.outT[b*1024 + i] = hn;
    }
    if (ic == 0 && tid < 128){
      __builtin_nontemporal_store(wf[tid], p.attw + ((size_t)(b*128 + t))*128 + tid);
    }
    target += 16; gbar(cnt, target);
  }
}

// ---------- logsumexp over V per output row, then in-place fixup ----------
__global__ __launch_bounds__(256) void lse_kernel(const float* __restrict__ outp, float* __restrict__ lse){
  __shared__ float rm[256], rs[256];
  int r = blockIdx.x, tid = threadIdx.x;
  const float4* rp = (const float4*)(outp + (size_t)r*32000);
  float m = -3.0e38f, s = 0.f;
  for (int v = tid; v < 8000; v += 256){
    float4 x = rp[v];
    float mx = fmaxf(fmaxf(x.x, x.y), fmaxf(x.z, x.w));
    if (mx > m){ s *= __expf(m - mx); m = mx; }
    s += __expf(x.x - m) + __expf(x.y - m) + __expf(x.z - m) + __expf(x.w - m);
  }
  rm[tid] = m; rs[tid] = s;
  __syncthreads();
  for (int o = 128; o; o >>= 1){
    if (tid < o){
      float m2 = rm[tid + o], s2 = rs[tid + o], m1 = rm[tid], s1 = rs[tid];
      float M = fmaxf(m1, m2);
      rs[tid] = s1*__expf(m1 - M) + s2*__expf(m2 - M);
      rm[tid] = M;
    }
    __syncthreads();
  }
  if (tid == 0) lse[r] = rm[0] + __logf(rs[0]);
}

__global__ __launch_bounds__(256) void fixup_kernel(float* __restrict__ outp, const float* __restrict__ lse){
  int idx = blockIdx.x*256 + threadIdx.x;
  int r = idx / 8000;
  float L = lse[r];
  float4* p4 = (float4*)outp;
  float4 u = p4[idx];
  u.x -= L; u.y -= L; u.z -= L; u.w -= L;
  p4[idx] = u;
}

// ---------- host ----------
extern "C" void kernel_launch(void* const* d_in, const int* in_sizes, int n_in,
                              void* d_out, int out_size, void* d_ws, size_t ws_size,
                              hipStream_t stream) {
  (void)in_sizes; (void)n_in; (void)out_size; (void)ws_size;
  const float* eo   = (const float*)d_in[0];
  const float* eh   = (const float*)d_in[1];
  const int*   tgt  = (const int*)d_in[2];
  const float* emb  = (const float*)d_in[3];
  const float* Wq   = (const float*)d_in[4];
  const float* Wk   = (const float*)d_in[5];
  const float* vatt = (const float*)d_in[6];
  const float* Wih  = (const float*)d_in[7];
  const float* Whh  = (const float*)d_in[8];
  const float* bih  = (const float*)d_in[9];
  const float* bhh  = (const float*)d_in[10];
  const float* Wout = (const float*)d_in[11];
  const float* bout = (const float*)d_in[12];
  float* out = (float*)d_out;

  char* ws = (char*)d_ws;
  u16*  kproj = (u16*) (ws + 0);          //  4 MiB  [16*128][1024] bf16
  u16*  ge    = (u16*) (ws + 4194304);    // 12 MiB  [128*16][3072] bf16 (incl b_ih)
  u16*  Pt    = (u16*) (ws + 16777216);   // 12 MiB  [16][3072][128] bf16
  u16*  eall  = (u16*) (ws + 29360128);   //  4 MiB  [128*16][1024] bf16
  u16*  hseq  = (u16*) (ws + 33554432);   //  4 MiB  [128*16][1024] bf16
  u16*  wc2   = (u16*) (ws + 37748736);   //  8 MiB  rearranged [4096][1024] bf16
  float* hf   = (float*)(ws + 46137344);  // 64 KiB  [16][1024] f32
  int*  bar   = (int*)  (ws + 46202880);  // 32 KiB  group-barrier counters
  float* psc  = (float*)(ws + 46235648);  // 128 KiB [16][128][16] partial scores
  float* lse  = (float*)(ws + 46505984);  //  8 KiB

  float* outT = out + 65536000;
  float* attw = out + 65552384;

  cast_w2<<<4096, 128, 0, stream>>>(Wq, Whh, wc2);
  gather_e<<<2048, 128, 0, stream>>>(tgt, emb, eall);
  init_h<<<64, 256, 0, stream>>>(eh, hf, bar);

  gemm_bt<1, true, true><<<dim3(8, 16), 256, 0, stream>>>(eo, 1024, Wk, 1024, kproj, nullptr, 1024, 1024);
  gemm_bt<1, false, true><<<dim3(24, 16), 256, 0, stream>>>(eall, 1024, Wih, 2048, ge, bih, 1024, 3072);
  gemm_bt<3, true, true><<<dim3(24, 16), 256, 0, stream>>>(eo, 1024, Wih + 1024, 2048, Pt, nullptr, 1024, 3072);

  RP rp;
  rp.Wc2 = wc2; rp.kproj = kproj; rp.Pt = Pt; rp.ge = ge;
  rp.bhh = bhh; rp.vatt = vatt;
  rp.psc = psc; rp.hf = hf;
  rp.hseq = hseq; rp.outT = outT; rp.attw = attw;
  rp.bar = bar;
  void* kargs[] = { (void*)&rp };
  hipLaunchCooperativeKernel((void*)rec_kernel, dim3(256), dim3(512), kargs, 0, stream);

  gemm_bt<2, false, true><<<dim3(250, 16), 256, 0, stream>>>(hseq, 1024, Wout, 1024, out, bout, 1024, 32000);
  lse_kernel<<<2048, 256, 0, stream>>>(out, lse);
  fixup_kernel<<<64000, 256, 0, stream>>>(out, lse);
}